// Round 2
// baseline (142.951 us; speedup 1.0000x reference)
//
#include <hip/hip_runtime.h>

// TripletLossMultipleMargins: mean(relu(|a-p|^2 - |a-n|^2 + M[al, nl]))
// B=1048576, D=64, N_CLASSES=10. Memory-bound streaming reduction.
// R1: 4x row unroll for memory-level parallelism (R0 was latency-bound:
//     VGPR=16, only 3 loads in flight, HBM at 27% peak).

namespace {
constexpr int kB           = 1048576;
constexpr int kNC          = 10;
constexpr int kBlock       = 256;
constexpr int kLanesPerRow = 16;                     // 16 lanes x float4 = 64 floats = D
constexpr int kRowsPerBlk  = kBlock / kLanesPerRow;  // 16 rows per sub-iteration
constexpr int kUnroll      = 4;                      // rows per thread per iteration
constexpr int kRowsPerIter = kRowsPerBlk * kUnroll;  // 64 rows per block-iteration
constexpr int kGrid        = 2048;                   // kB / (kGrid*kRowsPerIter) = 8 iters
}

__global__ __launch_bounds__(kBlock) void triplet_partial_kernel(
    const float4* __restrict__ a,
    const float4* __restrict__ p,
    const float4* __restrict__ n,
    const int*    __restrict__ alab,
    const int*    __restrict__ nlab,
    const float*  __restrict__ mm,
    float*        __restrict__ partials)
{
    __shared__ float s_m[kNC * kNC];
    for (int i = threadIdx.x; i < kNC * kNC; i += kBlock) s_m[i] = mm[i];
    __syncthreads();

    const int j   = threadIdx.x & (kLanesPerRow - 1);
    const int rib = threadIdx.x / kLanesPerRow;

    float acc = 0.0f;

    // kB % (kGrid*kRowsPerIter) == 0 -> every row in-bounds, no tail branch.
    #pragma unroll 1
    for (int base = blockIdx.x * kRowsPerIter; base < kB;
         base += kGrid * kRowsPerIter) {
        const int r0 = base + rib;

        // ---- batch all 12 global loads first (max loads in flight) ----
        float4 av[kUnroll], pv[kUnroll], nv[kUnroll];
        #pragma unroll
        for (int u = 0; u < kUnroll; ++u) {
            const int idx = (r0 + u * kRowsPerBlk) * kLanesPerRow + j;
            av[u] = a[idx];
            pv[u] = p[idx];
            nv[u] = n[idx];
        }

        // ---- label loads early: latency hides under the shuffle chains ----
        int al[kUnroll], nl[kUnroll];
        if (j == 0) {
            #pragma unroll
            for (int u = 0; u < kUnroll; ++u) {
                const int r = r0 + u * kRowsPerBlk;
                al[u] = alab[r];
                nl[u] = nlab[r];
            }
        }

        // ---- compute per-lane partial diffs ----
        float diff[kUnroll];
        #pragma unroll
        for (int u = 0; u < kUnroll; ++u) {
            float d, dp = 0.0f, dn = 0.0f;
            d = av[u].x - pv[u].x; dp = fmaf(d, d, dp);
            d = av[u].y - pv[u].y; dp = fmaf(d, d, dp);
            d = av[u].z - pv[u].z; dp = fmaf(d, d, dp);
            d = av[u].w - pv[u].w; dp = fmaf(d, d, dp);
            d = av[u].x - nv[u].x; dn = fmaf(d, d, dn);
            d = av[u].y - nv[u].y; dn = fmaf(d, d, dn);
            d = av[u].z - nv[u].z; dn = fmaf(d, d, dn);
            d = av[u].w - nv[u].w; dn = fmaf(d, d, dn);
            diff[u] = dp - dn;
        }

        // ---- 4 independent shuffle-reduce chains (latencies overlap) ----
        #pragma unroll
        for (int m = 8; m >= 1; m >>= 1) {
            #pragma unroll
            for (int u = 0; u < kUnroll; ++u)
                diff[u] += __shfl_xor(diff[u], m, 64);
        }

        if (j == 0) {
            #pragma unroll
            for (int u = 0; u < kUnroll; ++u) {
                const float loss = diff[u] + s_m[al[u] * kNC + nl[u]];
                acc += (loss > 0.0f) ? loss : 0.0f;
            }
        }
    }

    // block-wide reduction (acc is zero on j!=0 lanes; summing all is fine)
    #pragma unroll
    for (int m = 32; m >= 1; m >>= 1) acc += __shfl_xor(acc, m, 64);
    __shared__ float s_red[kBlock / 64];
    if ((threadIdx.x & 63) == 0) s_red[threadIdx.x >> 6] = acc;
    __syncthreads();
    if (threadIdx.x == 0) {
        float s = 0.0f;
        #pragma unroll
        for (int w = 0; w < kBlock / 64; ++w) s += s_red[w];
        partials[blockIdx.x] = s;
    }
}

__global__ __launch_bounds__(256) void triplet_finalize_kernel(
    const float* __restrict__ partials, float* __restrict__ out, int g)
{
    float acc = 0.0f;
    for (int i = threadIdx.x; i < g; i += 256) acc += partials[i];
    #pragma unroll
    for (int m = 32; m >= 1; m >>= 1) acc += __shfl_xor(acc, m, 64);
    __shared__ float s_red[4];
    if ((threadIdx.x & 63) == 0) s_red[threadIdx.x >> 6] = acc;
    __syncthreads();
    if (threadIdx.x == 0) {
        out[0] = (s_red[0] + s_red[1] + s_red[2] + s_red[3]) * (1.0f / (float)kB);
    }
}

extern "C" void kernel_launch(void* const* d_in, const int* in_sizes, int n_in,
                              void* d_out, int out_size, void* d_ws, size_t ws_size,
                              hipStream_t stream) {
    const float4* a    = (const float4*)d_in[0];
    const float4* p    = (const float4*)d_in[1];
    const float4* n    = (const float4*)d_in[2];
    const int*    alab = (const int*)d_in[3];
    const int*    nlab = (const int*)d_in[4];
    const float*  mm   = (const float*)d_in[5];

    float* partials = (float*)d_ws;           // kGrid floats, fully overwritten
    float* out      = (float*)d_out;

    triplet_partial_kernel<<<kGrid, kBlock, 0, stream>>>(a, p, n, alab, nlab, mm, partials);
    triplet_finalize_kernel<<<1, 256, 0, stream>>>(partials, out, kGrid);
}

// Round 4
// 127.160 us; speedup vs baseline: 1.1242x; 1.1242x over previous
//
#include <hip/hip_runtime.h>

// TripletLossMultipleMargins: mean(relu(|a-p|^2 - |a-n|^2 + M[al, nl]))
// B=1048576, D=64, N_CLASSES=10. Memory-bound streaming reduction.
// R1 lesson: not MLP-bound — delivered-BW bound at ~5.6 TB/s aggregate
//   (~2.9 HBM + ~2.7 L3; caches persist across graph replays).
// R2/R3: anchor is exactly 256 MiB = L3 size. Mark positive/negative loads
//   non-temporal (evict-first, don't thrash L3) so anchor stays resident;
//   NT streams flow at full HBM rate. (R3: use clang ext_vector type —
//   __builtin_nontemporal_load rejects HIP_vector_type.)

namespace {
constexpr int kB           = 1048576;
constexpr int kNC          = 10;
constexpr int kBlock       = 256;
constexpr int kLanesPerRow = 16;                     // 16 lanes x float4 = D
constexpr int kRowsPerBlk  = kBlock / kLanesPerRow;  // 16 rows per sub-iteration
constexpr int kUnroll      = 2;
constexpr int kRowsPerIter = kRowsPerBlk * kUnroll;  // 32 rows per block-iteration
constexpr int kGrid        = 2048;                   // kB/(kGrid*kRowsPerIter)=16 iters

typedef float vfloat4 __attribute__((ext_vector_type(4)));
}

__global__ __launch_bounds__(kBlock) void triplet_partial_kernel(
    const vfloat4* __restrict__ a,
    const vfloat4* __restrict__ p,
    const vfloat4* __restrict__ n,
    const int*     __restrict__ alab,
    const int*     __restrict__ nlab,
    const float*   __restrict__ mm,
    float*         __restrict__ partials)
{
    __shared__ float s_m[kNC * kNC];
    for (int i = threadIdx.x; i < kNC * kNC; i += kBlock) s_m[i] = mm[i];
    __syncthreads();

    const int j   = threadIdx.x & (kLanesPerRow - 1);
    const int rib = threadIdx.x / kLanesPerRow;

    float acc = 0.0f;

    #pragma unroll 1
    for (int base = blockIdx.x * kRowsPerIter; base < kB;
         base += kGrid * kRowsPerIter) {
        const int r0 = base + rib;

        vfloat4 av[kUnroll], pv[kUnroll], nv[kUnroll];
        #pragma unroll
        for (int u = 0; u < kUnroll; ++u) {
            const int idx = (r0 + u * kRowsPerBlk) * kLanesPerRow + j;
            av[u] = a[idx];                              // normal: L3-resident
            pv[u] = __builtin_nontemporal_load(&p[idx]); // NT: stream, don't thrash
            nv[u] = __builtin_nontemporal_load(&n[idx]); // NT: stream, don't thrash
        }

        int al[kUnroll], nl[kUnroll];
        if (j == 0) {
            #pragma unroll
            for (int u = 0; u < kUnroll; ++u) {
                const int r = r0 + u * kRowsPerBlk;
                al[u] = alab[r];
                nl[u] = nlab[r];
            }
        }

        float diff[kUnroll];
        #pragma unroll
        for (int u = 0; u < kUnroll; ++u) {
            float d, dp = 0.0f, dn = 0.0f;
            d = av[u].x - pv[u].x; dp = fmaf(d, d, dp);
            d = av[u].y - pv[u].y; dp = fmaf(d, d, dp);
            d = av[u].z - pv[u].z; dp = fmaf(d, d, dp);
            d = av[u].w - pv[u].w; dp = fmaf(d, d, dp);
            d = av[u].x - nv[u].x; dn = fmaf(d, d, dn);
            d = av[u].y - nv[u].y; dn = fmaf(d, d, dn);
            d = av[u].z - nv[u].z; dn = fmaf(d, d, dn);
            d = av[u].w - nv[u].w; dn = fmaf(d, d, dn);
            diff[u] = dp - dn;
        }

        #pragma unroll
        for (int m = 8; m >= 1; m >>= 1) {
            #pragma unroll
            for (int u = 0; u < kUnroll; ++u)
                diff[u] += __shfl_xor(diff[u], m, 64);
        }

        if (j == 0) {
            #pragma unroll
            for (int u = 0; u < kUnroll; ++u) {
                const float loss = diff[u] + s_m[al[u] * kNC + nl[u]];
                acc += (loss > 0.0f) ? loss : 0.0f;
            }
        }
    }

    #pragma unroll
    for (int m = 32; m >= 1; m >>= 1) acc += __shfl_xor(acc, m, 64);
    __shared__ float s_red[kBlock / 64];
    if ((threadIdx.x & 63) == 0) s_red[threadIdx.x >> 6] = acc;
    __syncthreads();
    if (threadIdx.x == 0) {
        float s = 0.0f;
        #pragma unroll
        for (int w = 0; w < kBlock / 64; ++w) s += s_red[w];
        partials[blockIdx.x] = s;
    }
}

__global__ __launch_bounds__(256) void triplet_finalize_kernel(
    const float* __restrict__ partials, float* __restrict__ out, int g)
{
    float acc = 0.0f;
    for (int i = threadIdx.x; i < g; i += 256) acc += partials[i];
    #pragma unroll
    for (int m = 32; m >= 1; m >>= 1) acc += __shfl_xor(acc, m, 64);
    __shared__ float s_red[4];
    if ((threadIdx.x & 63) == 0) s_red[threadIdx.x >> 6] = acc;
    __syncthreads();
    if (threadIdx.x == 0) {
        out[0] = (s_red[0] + s_red[1] + s_red[2] + s_red[3]) * (1.0f / (float)kB);
    }
}

extern "C" void kernel_launch(void* const* d_in, const int* in_sizes, int n_in,
                              void* d_out, int out_size, void* d_ws, size_t ws_size,
                              hipStream_t stream) {
    const vfloat4* a    = (const vfloat4*)d_in[0];
    const vfloat4* p    = (const vfloat4*)d_in[1];
    const vfloat4* n    = (const vfloat4*)d_in[2];
    const int*     alab = (const int*)d_in[3];
    const int*     nlab = (const int*)d_in[4];
    const float*   mm   = (const float*)d_in[5];

    float* partials = (float*)d_ws;           // kGrid floats, fully overwritten
    float* out      = (float*)d_out;

    triplet_partial_kernel<<<kGrid, kBlock, 0, stream>>>(a, p, n, alab, nlab, mm, partials);
    triplet_finalize_kernel<<<1, 256, 0, stream>>>(partials, out, kGrid);
}